// Round 3
// baseline (885.736 us; speedup 1.0000x reference)
//
#include <hip/hip_runtime.h>

#define B_  32
#define S_  2048
#define H_  1024
#define A_  256
#define L_  10

typedef unsigned short u16;
typedef __bf16 bf16_t;
typedef bf16_t bfv8 __attribute__((ext_vector_type(8)));
typedef float  f32x4 __attribute__((ext_vector_type(4)));
typedef u16    u16x4 __attribute__((ext_vector_type(4)));

__device__ __forceinline__ u16 f2bf(float f) {
    unsigned int u = __builtin_bit_cast(unsigned int, f);
    u += 0x7FFFu + ((u >> 16) & 1u);            // RNE
    return (u16)(u >> 16);
}
__device__ __forceinline__ float bf2f(u16 h) {
    unsigned int u = ((unsigned int)h) << 16;
    return __builtin_bit_cast(float, u);
}

typedef __attribute__((address_space(1))) const unsigned int gu32_t;
typedef __attribute__((address_space(3))) unsigned int lu32_t;
__device__ __forceinline__ void glds16(const void* g, void* l) {
    // async global->LDS, 16 B/lane; LDS dst = wave-uniform base + lane*16
    __builtin_amdgcn_global_load_lds((gu32_t*)g, (lu32_t*)l, 16, 0, 0);
}

__device__ __forceinline__ void split4(float4 v, u16x4& h4, u16x4& l4) {
    float a0 = v.x, a1 = v.y, a2 = v.z, a3 = v.w;
    u16 h;
    h = f2bf(a0); h4[0] = h; l4[0] = f2bf(a0 - bf2f(h));
    h = f2bf(a1); h4[1] = h; l4[1] = f2bf(a1 - bf2f(h));
    h = f2bf(a2); h4[2] = h; l4[2] = f2bf(a2 - bf2f(h));
    h = f2bf(a3); h4[3] = h; l4[3] = f2bf(a3 - bf2f(h));
}

// ---------------------------------------------------------------------------
// pack_weights: W1 [L][H][A] and W2 [L][A][H] -> MFMA B-frag order hi/lo planes.
// Fragment slot = lane*8+i  <->  k = ktile*32 + (lane>>4)*8+i, n = nt*16 + (lane&15)
// w1 layout: [lid][ktg(32)][nt(16)][512]; w2: [lid][kt(8)][nt(64)][512].
// One block = one 32k x 256n source patch, coalesced read -> LDS -> coalesced write.
// ---------------------------------------------------------------------------
__global__ __launch_bounds__(256) void pack_weights(
    const float* __restrict__ W1, const float* __restrict__ W2,
    u16* __restrict__ w1h, u16* __restrict__ w1l,
    u16* __restrict__ w2h, u16* __restrict__ w2l)
{
    __shared__ float lds[32][264];
    const int p = blockIdx.x;
    const float* src; int sstride; u16 *dh, *dl; size_t dbase;
    if (p < 320) {                       // W1: (lid, ktg)
        int lid = p >> 5, ktg = p & 31;
        src = W1 + ((size_t)lid * H_ + ktg * 32) * A_;
        sstride = A_;
        dh = w1h; dl = w1l;
        dbase = (size_t)(lid * 32 + ktg) * 8192;
    } else {                             // W2: (lid, kt, nquarter)
        int p2 = p - 320;
        int lid = p2 >> 5, kt = (p2 >> 2) & 7, nq = p2 & 3;
        src = W2 + ((size_t)lid * A_ + kt * 32) * H_ + nq * 256;
        sstride = H_;
        dh = w2h; dl = w2l;
        dbase = ((size_t)(lid * 8 + kt) * 64 + nq * 16) * 512;
    }
    const int t = threadIdx.x;
    #pragma unroll
    for (int j = 0; j < 8; ++j) {        // 32 rows x 256 cols fp32, coalesced
        int row = j * 4 + (t >> 6);
        int c4  = (t & 63) * 4;
        float4 v = *(const float4*)(src + (size_t)row * sstride + c4);
        *(float4*)&lds[row][c4] = v;
    }
    __syncthreads();
    #pragma unroll
    for (int j = 0; j < 32; ++j) {       // 8192 fragment slots, coalesced writes
        int q    = j * 256 + t;
        int slot = q & 511, tl = q >> 9;
        int ln   = slot >> 3, i = slot & 7;
        int kl   = ((ln >> 4) << 3) + i;
        int n    = tl * 16 + (ln & 15);
        float v  = lds[kl][n];
        u16 hi   = f2bf(v);
        dh[dbase + q] = hi;
        dl[dbase + q] = f2bf(v - bf2f(hi));
    }
}

// ---------------------------------------------------------------------------
// Fused: h = relu(X@W1+b1) kept in LDS; out = LN(X + h@W2 + b2)*gamma + beta.
// Block = 64 rows x full H, 512 thr (8 waves, 2m x 4n). 1 block/CU (LDS 148KB).
// Phase 1: K=1024 in 32 steps of 32; X staged hi/lo in LDS (single buf,
//   reg-prefetched), W1 via global_load_lds double-buffered.
// Phase 2: K=256, N=1024 in 4 quarters; W2 via global_load_lds ping-pong
//   (stage quarter q+1 while MFMA quarter q); h read from swizzled LDS.
// LDS map (dynamic 152064 B):
//   [0,65536)        h hi/lo planes [64][256] u16, XOR-swizzled (k ^ ((row&7)<<3))
//   [65536,83968)    phase1 xbuf [2pl][64][72] u16        (pad 72 vs conflicts)
//   [83968,149504)   phase1 w1buf [2buf][2pl][16][512] u16
//   [65536,131072)   phase2 w2buf [2buf][2pl][16][512] u16 (time-disjoint w/ xbuf)
//   [149504,152064)  LN scratch part[64][4][2] + mrstd[64][2]
// ---------------------------------------------------------------------------
__global__ __launch_bounds__(512) void fused_adapter(
    const float* __restrict__ X, const int* __restrict__ langs,
    const float* __restrict__ b1, const float* __restrict__ b2,
    const float* __restrict__ gamma, const float* __restrict__ beta,
    const u16* __restrict__ w1h, const u16* __restrict__ w1l,
    const u16* __restrict__ w2h, const u16* __restrict__ w2l,
    float* __restrict__ out)
{
    extern __shared__ char smem[];
    u16*   hh    = (u16*)smem;                 // [64][256]
    u16*   hl    = (u16*)(smem + 32768);
    u16*   xbuf  = (u16*)(smem + 65536);       // [2pl][64][72]
    u16*   w1b   = (u16*)(smem + 83968);       // [2][2][16][512]
    u16*   w2b   = (u16*)(smem + 65536);       // [2][2][16][512]
    float* part  = (float*)(smem + 149504);    // [64][4][2]
    float* mrstd = (float*)(smem + 151552);    // [64][2]

    // XCD-aware swizzle: XCD k serves batches 4k..4k+3 (one language at a time
    // per XCD -> W1/W2 packed planes stay L2-resident).
    const int fid = blockIdx.x;
    const int uu  = fid >> 3;
    const int b   = (fid & 7) * 4 + (uu >> 5);
    const int s0  = (uu & 31) * 64;
    const int lid = langs[b];

    const int t = threadIdx.x, lane = t & 63, wid = t >> 6;
    const int wm = wid >> 2, wn = wid & 3;
    const int lr = lane & 15, lg = lane >> 4;

    const float* Xb = X + ((size_t)(b * S_ + s0)) * H_;

    // ======================= phase 1 =======================
    f32x4 acc1[2][4];
    #pragma unroll
    for (int mf = 0; mf < 2; ++mf)
        #pragma unroll
        for (int nf = 0; nf < 4; ++nf) acc1[mf][nf] = f32x4{0.f, 0.f, 0.f, 0.f};

    const int srow = t >> 3, skg = (t & 7) * 4;   // X staging: 64 rows x 32 k

    { // prologue: stage kt=0
        float4 xv = *(const float4*)(Xb + (size_t)srow * H_ + skg);
        #pragma unroll
        for (int j = 0; j < 4; ++j) {
            int idx = wid * 4 + j, pl = idx >> 4, nt = idx & 15;
            const u16* g = (pl ? w1l : w1h) + ((size_t)(lid * 32 + 0) * 16 + nt) * 512 + lane * 8;
            glds16(g, w1b + ((0 * 2 + pl) * 16 + nt) * 512);
        }
        u16x4 h4, l4; split4(xv, h4, l4);
        *(u16x4*)(xbuf + srow * 72 + skg)        = h4;
        *(u16x4*)(xbuf + 4608 + srow * 72 + skg) = l4;
        __syncthreads();
    }

    #pragma unroll 1
    for (int kt = 0; kt < 32; ++kt) {
        float4 xv;
        if (kt < 31) {   // issue next-step staging early (uniform branch)
            xv = *(const float4*)(Xb + (size_t)srow * H_ + (kt + 1) * 32 + skg);
            #pragma unroll
            for (int j = 0; j < 4; ++j) {
                int idx = wid * 4 + j, pl = idx >> 4, nt = idx & 15;
                const u16* g = (pl ? w1l : w1h) + ((size_t)(lid * 32 + kt + 1) * 16 + nt) * 512 + lane * 8;
                glds16(g, w1b + ((((kt + 1) & 1) * 2 + pl) * 16 + nt) * 512);
            }
        }
        bfv8 ah[2], al[2];
        #pragma unroll
        for (int mf = 0; mf < 2; ++mf) {
            int row = wm * 32 + mf * 16 + lr;
            ah[mf] = *(const bfv8*)(xbuf + row * 72 + lg * 8);
            al[mf] = *(const bfv8*)(xbuf + 4608 + row * 72 + lg * 8);
        }
        const u16* wb = w1b + (kt & 1) * 16384;
        #pragma unroll
        for (int nf = 0; nf < 4; ++nf) {
            int nt = wn * 4 + nf;
            bfv8 bh = *(const bfv8*)(wb + nt * 512 + lane * 8);
            bfv8 bl = *(const bfv8*)(wb + 8192 + nt * 512 + lane * 8);
            #pragma unroll
            for (int mf = 0; mf < 2; ++mf) {
                acc1[mf][nf] = __builtin_amdgcn_mfma_f32_16x16x32_bf16(ah[mf], bh, acc1[mf][nf], 0, 0, 0);
                acc1[mf][nf] = __builtin_amdgcn_mfma_f32_16x16x32_bf16(ah[mf], bl, acc1[mf][nf], 0, 0, 0);
                acc1[mf][nf] = __builtin_amdgcn_mfma_f32_16x16x32_bf16(al[mf], bh, acc1[mf][nf], 0, 0, 0);
            }
        }
        __syncthreads();                 // xbuf reads done; own glds drained
        if (kt < 31) {
            u16x4 h4, l4; split4(xv, h4, l4);
            *(u16x4*)(xbuf + srow * 72 + skg)        = h4;
            *(u16x4*)(xbuf + 4608 + srow * 72 + skg) = l4;
        }
        __syncthreads();                 // xbuf(kt+1) visible
    }

    // epilogue-1: bias+relu -> swizzled h planes in LDS
    #pragma unroll
    for (int mf = 0; mf < 2; ++mf)
        #pragma unroll
        for (int nf = 0; nf < 4; ++nf) {
            int k = wn * 64 + nf * 16 + lr;          // h's k index
            float bias = b1[lid * A_ + k];
            #pragma unroll
            for (int r = 0; r < 4; ++r) {
                int row = wm * 32 + mf * 16 + lg * 4 + r;
                float v = acc1[mf][nf][r] + bias;
                v = v > 0.f ? v : 0.f;
                int sw = (row & 7) << 3;
                u16 hi = f2bf(v);
                hh[row * 256 + (k ^ sw)] = hi;
                hl[row * 256 + (k ^ sw)] = f2bf(v - bf2f(hi));
            }
        }
    // prologue-2: stage (kt=0, q=0)
    #pragma unroll
    for (int j = 0; j < 4; ++j) {
        int idx = wid * 4 + j, pl = idx >> 4, tl = idx & 15;
        const u16* g = (pl ? w2l : w2h) + ((size_t)(lid * 8 + 0) * 64 + tl) * 512 + lane * 8;
        glds16(g, w2b + ((0 * 2 + pl) * 16 + tl) * 512);
    }
    __syncthreads();                     // h visible + w2 buf0 ready

    // ======================= phase 2 =======================
    f32x4 acc2[2][4][4];                 // [mf][q][nf]
    #pragma unroll
    for (int mf = 0; mf < 2; ++mf)
        #pragma unroll
        for (int q = 0; q < 4; ++q)
            #pragma unroll
            for (int nf = 0; nf < 4; ++nf) acc2[mf][q][nf] = f32x4{0.f, 0.f, 0.f, 0.f};

    bfv8 a2h[2], a2l[2];
    #pragma unroll
    for (int kt = 0; kt < 8; ++kt) {
        #pragma unroll
        for (int q = 0; q < 4; ++q) {
            const int ph = kt * 4 + q, pbuf = ph & 1;
            if (ph < 31) {               // stage next phase into other buffer
                int kn = (ph + 1) >> 2, qn = (ph + 1) & 3;
                #pragma unroll
                for (int j = 0; j < 4; ++j) {
                    int idx = wid * 4 + j, pl = idx >> 4, tl = idx & 15;
                    const u16* g = (pl ? w2l : w2h) + ((size_t)(lid * 8 + kn) * 64 + qn * 16 + tl) * 512 + lane * 8;
                    glds16(g, w2b + (((pbuf ^ 1) * 2 + pl) * 16 + tl) * 512);
                }
            }
            if (q == 0) {                // h A-frags, reused across 4 quarters
                #pragma unroll
                for (int mf = 0; mf < 2; ++mf) {
                    int row = wm * 32 + mf * 16 + lr;
                    int sw  = (row & 7) << 3;
                    a2h[mf] = *(const bfv8*)(hh + row * 256 + ((kt * 32 + lg * 8) ^ sw));
                    a2l[mf] = *(const bfv8*)(hl + row * 256 + ((kt * 32 + lg * 8) ^ sw));
                }
            }
            const u16* wb2 = w2b + pbuf * 16384;
            #pragma unroll
            for (int nf = 0; nf < 4; ++nf) {
                int tl = wn * 4 + nf;
                bfv8 bh = *(const bfv8*)(wb2 + tl * 512 + lane * 8);
                bfv8 bl = *(const bfv8*)(wb2 + 8192 + tl * 512 + lane * 8);
                #pragma unroll
                for (int mf = 0; mf < 2; ++mf) {
                    acc2[mf][q][nf] = __builtin_amdgcn_mfma_f32_16x16x32_bf16(a2h[mf], bh, acc2[mf][q][nf], 0, 0, 0);
                    acc2[mf][q][nf] = __builtin_amdgcn_mfma_f32_16x16x32_bf16(a2h[mf], bl, acc2[mf][q][nf], 0, 0, 0);
                    acc2[mf][q][nf] = __builtin_amdgcn_mfma_f32_16x16x32_bf16(a2l[mf], bh, acc2[mf][q][nf], 0, 0, 0);
                }
            }
            __syncthreads();
        }
    }

    // bias + residual + LN statistics
    float s1v[2][4], s2v[2][4];
    #pragma unroll
    for (int mf = 0; mf < 2; ++mf)
        #pragma unroll
        for (int r = 0; r < 4; ++r) { s1v[mf][r] = 0.f; s2v[mf][r] = 0.f; }

    #pragma unroll
    for (int mf = 0; mf < 2; ++mf)
        #pragma unroll
        for (int q = 0; q < 4; ++q)
            #pragma unroll
            for (int nf = 0; nf < 4; ++nf) {
                int col = (q * 16 + wn * 4 + nf) * 16 + lr;
                float bb = b2[lid * H_ + col];
                #pragma unroll
                for (int r = 0; r < 4; ++r) {
                    int row = wm * 32 + mf * 16 + lg * 4 + r;
                    float x = acc2[mf][q][nf][r] + bb + Xb[(size_t)row * H_ + col];
                    acc2[mf][q][nf][r] = x;
                    s1v[mf][r] += x; s2v[mf][r] += x * x;
                }
            }

    #pragma unroll
    for (int mf = 0; mf < 2; ++mf)
        #pragma unroll
        for (int r = 0; r < 4; ++r) {
            float a = s1v[mf][r], c = s2v[mf][r];
            #pragma unroll
            for (int m = 1; m < 16; m <<= 1) { a += __shfl_xor(a, m); c += __shfl_xor(c, m); }
            if (lr == 0) {
                int row = wm * 32 + mf * 16 + lg * 4 + r;
                part[(row * 4 + wn) * 2 + 0] = a;
                part[(row * 4 + wn) * 2 + 1] = c;
            }
        }
    __syncthreads();
    if (t < 64) {
        float a = part[(t*4+0)*2] + part[(t*4+1)*2] + part[(t*4+2)*2] + part[(t*4+3)*2];
        float c = part[(t*4+0)*2+1] + part[(t*4+1)*2+1] + part[(t*4+2)*2+1] + part[(t*4+3)*2+1];
        float mean = a * (1.f / 1024.f);
        float var  = c * (1.f / 1024.f) - mean * mean;
        mrstd[t*2]   = mean;
        mrstd[t*2+1] = rsqrtf(var + 1e-5f);
    }
    __syncthreads();

    float* ob = out + ((size_t)(b * S_ + s0)) * H_;
    #pragma unroll
    for (int q = 0; q < 4; ++q)
        #pragma unroll
        for (int nf = 0; nf < 4; ++nf) {
            int col = (q * 16 + wn * 4 + nf) * 16 + lr;
            float g  = gamma[lid * H_ + col];
            float bt = beta[lid * H_ + col];
            #pragma unroll
            for (int mf = 0; mf < 2; ++mf)
                #pragma unroll
                for (int r = 0; r < 4; ++r) {
                    int row = wm * 32 + mf * 16 + lg * 4 + r;
                    float x = acc2[mf][q][nf][r];
                    ob[(size_t)row * H_ + col] = (x - mrstd[row*2]) * mrstd[row*2+1] * g + bt;
                }
        }
}

// ---------------------------------------------------------------------------
extern "C" void kernel_launch(void* const* d_in, const int* in_sizes, int n_in,
                              void* d_out, int out_size, void* d_ws, size_t ws_size,
                              hipStream_t stream)
{
    const float* X     = (const float*)d_in[0];
    const int*   langs = (const int*)  d_in[1];
    const float* W1    = (const float*)d_in[2];
    const float* b1    = (const float*)d_in[3];
    const float* W2    = (const float*)d_in[4];
    const float* b2    = (const float*)d_in[5];
    const float* gamma = (const float*)d_in[6];
    const float* beta  = (const float*)d_in[7];
    float* out = (float*)d_out;

    char* ws = (char*)d_ws;
    u16* w1h = (u16*)(ws);
    u16* w1l = (u16*)(ws + 5242880);
    u16* w2h = (u16*)(ws + 10485760);
    u16* w2l = (u16*)(ws + 15728640);   // total 20,971,520 B of d_ws

    hipFuncSetAttribute((const void*)fused_adapter,
                        hipFuncAttributeMaxDynamicSharedMemorySize, 152064);

    hipLaunchKernelGGL(pack_weights, dim3(640), dim3(256), 0, stream,
                       W1, W2, w1h, w1l, w2h, w2l);
    hipLaunchKernelGGL(fused_adapter, dim3(1024), dim3(512), 152064, stream,
                       X, langs, b1, b2, gamma, beta, w1h, w1l, w2h, w2l, out);
}

// Round 5
// 828.615 us; speedup vs baseline: 1.0689x; 1.0689x over previous
//
#include <hip/hip_runtime.h>

#define B_  32
#define S_  2048
#define H_  1024
#define A_  256
#define L_  10

typedef unsigned short u16;
typedef __bf16 bf16_t;
typedef bf16_t bfv8 __attribute__((ext_vector_type(8)));
typedef float  f32x4 __attribute__((ext_vector_type(4)));
typedef u16    u16x4 __attribute__((ext_vector_type(4)));
typedef u16    u16x8 __attribute__((ext_vector_type(8)));

__device__ __forceinline__ u16 f2bf(float f) {
    unsigned int u = __builtin_bit_cast(unsigned int, f);
    u += 0x7FFFu + ((u >> 16) & 1u);            // RNE
    return (u16)(u >> 16);
}
__device__ __forceinline__ float bf2f(u16 h) {
    unsigned int u = ((unsigned int)h) << 16;
    return __builtin_bit_cast(float, u);
}

typedef __attribute__((address_space(1))) const unsigned int gu32_t;
typedef __attribute__((address_space(3))) unsigned int lu32_t;
__device__ __forceinline__ void glds16(const void* g, void* l) {
    // async global->LDS, 16 B/lane; LDS dst = wave-uniform base + lane*16
    __builtin_amdgcn_global_load_lds((gu32_t*)g, (lu32_t*)l, 16, 0, 0);
}

__device__ __forceinline__ void split4(float4 v, u16x4& h4, u16x4& l4) {
    float a0 = v.x, a1 = v.y, a2 = v.z, a3 = v.w;
    u16 h;
    h = f2bf(a0); h4[0] = h; l4[0] = f2bf(a0 - bf2f(h));
    h = f2bf(a1); h4[1] = h; l4[1] = f2bf(a1 - bf2f(h));
    h = f2bf(a2); h4[2] = h; l4[2] = f2bf(a2 - bf2f(h));
    h = f2bf(a3); h4[3] = h; l4[3] = f2bf(a3 - bf2f(h));
}

// ---------------------------------------------------------------------------
// pack_weights v2: direct gather, no LDS. Each lane owns fragment lane ln=t&63:
//   slot = ln*8 + i  <->  k = k0 + i (k0 = (ln>>4)*8), n = nt*16 + (ln&15).
// Reads: 8 floats stride-sstride (64B segments x 4 rows per inst, L2-cached).
// Writes: u16x8 (16 B/lane, fully coalesced per 512-slot tile).
// w1 layout: [lid][ktg(32)][nt(16)][512]; w2: [lid][kt(8)][nt(64)][512].
// ---------------------------------------------------------------------------
__global__ __launch_bounds__(256) void pack_weights(
    const float* __restrict__ W1, const float* __restrict__ W2,
    u16* __restrict__ w1h, u16* __restrict__ w1l,
    u16* __restrict__ w2h, u16* __restrict__ w2l)
{
    const int p = blockIdx.x;
    const int t = threadIdx.x;
    const float* src; int sstride; u16 *dh, *dl; size_t dbase;
    if (p < 320) {                       // W1: (lid, ktg) -> 32k x 256n patch
        int lid = p >> 5, ktg = p & 31;
        src = W1 + ((size_t)lid * H_ + ktg * 32) * A_;
        sstride = A_;
        dh = w1h; dl = w1l;
        dbase = (size_t)(lid * 32 + ktg) * 8192;
    } else {                             // W2: (lid, kt, nquarter)
        int p2 = p - 320;
        int lid = p2 >> 5, kt = (p2 >> 2) & 7, nq = p2 & 3;
        src = W2 + ((size_t)lid * A_ + kt * 32) * H_ + nq * 256;
        sstride = H_;
        dh = w2h; dl = w2l;
        dbase = ((size_t)(lid * 8 + kt) * 64 + nq * 16) * 512;
    }
    const int ln = t & 63;
    const int k0 = (ln >> 4) * 8;
    const int nn = ln & 15;
    #pragma unroll
    for (int r = 0; r < 4; ++r) {
        int nt = r * 4 + (t >> 6);       // tile 0..15 within the patch
        const float* s = src + (size_t)k0 * sstride + nt * 16 + nn;
        u16x8 h8, l8;
        #pragma unroll
        for (int i = 0; i < 8; ++i) {
            float v = s[(size_t)i * sstride];
            u16 hi = f2bf(v);
            h8[i] = hi; l8[i] = f2bf(v - bf2f(hi));
        }
        size_t q = dbase + (size_t)nt * 512 + (size_t)ln * 8;
        *(u16x8*)(dh + q) = h8;
        *(u16x8*)(dl + q) = l8;
    }
}

// ---------------------------------------------------------------------------
// Fused: h = relu(X@W1+b1) kept in LDS; out = LN(X + h@W2 + b2)*gamma + beta.
// Block = 64 rows x full H, 512 thr (8 waves, 2m x 4n). 1 block/CU (LDS 148KB).
// __launch_bounds__(512,2): 2 waves/SIMD is forced by the 512-thr block anyway;
// declares the 256-VGPR budget so acc2 (128 f32) does NOT spill to scratch.
// ---------------------------------------------------------------------------
__global__ __launch_bounds__(512, 2) void fused_adapter(
    const float* __restrict__ X, const int* __restrict__ langs,
    const float* __restrict__ b1, const float* __restrict__ b2,
    const float* __restrict__ gamma, const float* __restrict__ beta,
    const u16* __restrict__ w1h, const u16* __restrict__ w1l,
    const u16* __restrict__ w2h, const u16* __restrict__ w2l,
    float* __restrict__ out)
{
    extern __shared__ char smem[];
    u16*   hh    = (u16*)smem;                 // [64][256]
    u16*   hl    = (u16*)(smem + 32768);
    u16*   xbuf  = (u16*)(smem + 65536);       // [2pl][64][72]
    u16*   w1b   = (u16*)(smem + 83968);       // [2][2][16][512]
    u16*   w2b   = (u16*)(smem + 65536);       // [2][2][16][512]
    float* part  = (float*)(smem + 149504);    // [64][4][2]
    float* mrstd = (float*)(smem + 151552);    // [64][2]

    // XCD-aware swizzle: XCD k serves batches 4k..4k+3 (same lid for 32
    // consecutive blocks -> packed weights stay L2-resident).
    const int fid = blockIdx.x;
    const int uu  = fid >> 3;
    const int b   = (fid & 7) * 4 + (uu >> 5);
    const int s0  = (uu & 31) * 64;
    const int lid = langs[b];

    const int t = threadIdx.x, lane = t & 63, wid = t >> 6;
    const int wm = wid >> 2, wn = wid & 3;
    const int lr = lane & 15, lg = lane >> 4;

    const float* Xb = X + ((size_t)(b * S_ + s0)) * H_;

    // ======================= phase 1 =======================
    f32x4 acc1[2][4];
    #pragma unroll
    for (int mf = 0; mf < 2; ++mf)
        #pragma unroll
        for (int nf = 0; nf < 4; ++nf) acc1[mf][nf] = f32x4{0.f, 0.f, 0.f, 0.f};

    const int srow = t >> 3, skg = (t & 7) * 4;   // X staging: 64 rows x 32 k

    { // prologue: stage kt=0
        float4 xv = *(const float4*)(Xb + (size_t)srow * H_ + skg);
        #pragma unroll
        for (int j = 0; j < 4; ++j) {
            int idx = wid * 4 + j, pl = idx >> 4, nt = idx & 15;
            const u16* g = (pl ? w1l : w1h) + ((size_t)(lid * 32 + 0) * 16 + nt) * 512 + lane * 8;
            glds16(g, w1b + ((0 * 2 + pl) * 16 + nt) * 512);
        }
        u16x4 h4, l4; split4(xv, h4, l4);
        *(u16x4*)(xbuf + srow * 72 + skg)        = h4;
        *(u16x4*)(xbuf + 4608 + srow * 72 + skg) = l4;
        __syncthreads();
    }

    #pragma unroll 1
    for (int kt = 0; kt < 32; ++kt) {
        float4 xv;
        if (kt < 31) {   // issue next-step staging early (uniform branch)
            xv = *(const float4*)(Xb + (size_t)srow * H_ + (kt + 1) * 32 + skg);
            #pragma unroll
            for (int j = 0; j < 4; ++j) {
                int idx = wid * 4 + j, pl = idx >> 4, nt = idx & 15;
                const u16* g = (pl ? w1l : w1h) + ((size_t)(lid * 32 + kt + 1) * 16 + nt) * 512 + lane * 8;
                glds16(g, w1b + ((((kt + 1) & 1) * 2 + pl) * 16 + nt) * 512);
            }
        }
        bfv8 ah[2], al[2];
        #pragma unroll
        for (int mf = 0; mf < 2; ++mf) {
            int row = wm * 32 + mf * 16 + lr;
            ah[mf] = *(const bfv8*)(xbuf + row * 72 + lg * 8);
            al[mf] = *(const bfv8*)(xbuf + 4608 + row * 72 + lg * 8);
        }
        const u16* wb = w1b + (kt & 1) * 16384;
        #pragma unroll
        for (int nf = 0; nf < 4; ++nf) {
            int nt = wn * 4 + nf;
            bfv8 bh = *(const bfv8*)(wb + nt * 512 + lane * 8);
            bfv8 bl = *(const bfv8*)(wb + 8192 + nt * 512 + lane * 8);
            #pragma unroll
            for (int mf = 0; mf < 2; ++mf) {
                acc1[mf][nf] = __builtin_amdgcn_mfma_f32_16x16x32_bf16(ah[mf], bh, acc1[mf][nf], 0, 0, 0);
                acc1[mf][nf] = __builtin_amdgcn_mfma_f32_16x16x32_bf16(ah[mf], bl, acc1[mf][nf], 0, 0, 0);
                acc1[mf][nf] = __builtin_amdgcn_mfma_f32_16x16x32_bf16(al[mf], bh, acc1[mf][nf], 0, 0, 0);
            }
        }
        __syncthreads();                 // xbuf reads done; own glds drained
        if (kt < 31) {
            u16x4 h4, l4; split4(xv, h4, l4);
            *(u16x4*)(xbuf + srow * 72 + skg)        = h4;
            *(u16x4*)(xbuf + 4608 + srow * 72 + skg) = l4;
        }
        __syncthreads();                 // xbuf(kt+1) visible
    }

    // epilogue-1: bias+relu -> swizzled h planes in LDS
    #pragma unroll
    for (int mf = 0; mf < 2; ++mf)
        #pragma unroll
        for (int nf = 0; nf < 4; ++nf) {
            int k = wn * 64 + nf * 16 + lr;          // h's k index
            float bias = b1[lid * A_ + k];
            #pragma unroll
            for (int r = 0; r < 4; ++r) {
                int row = wm * 32 + mf * 16 + lg * 4 + r;
                float v = acc1[mf][nf][r] + bias;
                v = v > 0.f ? v : 0.f;
                int sw = (row & 7) << 3;
                u16 hi = f2bf(v);
                hh[row * 256 + (k ^ sw)] = hi;
                hl[row * 256 + (k ^ sw)] = f2bf(v - bf2f(hi));
            }
        }
    // prologue-2: stage (kt=0, q=0) into buf0
    #pragma unroll
    for (int j = 0; j < 4; ++j) {
        int idx = wid * 4 + j, pl = idx >> 4, tl = idx & 15;
        const u16* g = (pl ? w2l : w2h) + ((size_t)(lid * 8 + 0) * 64 + tl) * 512 + lane * 8;
        glds16(g, w2b + ((0 * 2 + pl) * 16 + tl) * 512);
    }
    __syncthreads();                     // h visible + w2 buf0 ready

    // ======================= phase 2 =======================
    f32x4 acc2[2][4][4];                 // [mf][q][nf]
    #pragma unroll
    for (int mf = 0; mf < 2; ++mf)
        #pragma unroll
        for (int q = 0; q < 4; ++q)
            #pragma unroll
            for (int nf = 0; nf < 4; ++nf) acc2[mf][q][nf] = f32x4{0.f, 0.f, 0.f, 0.f};

    bfv8 a2h[2], a2l[2];
    #pragma unroll 1
    for (int kt = 0; kt < 8; ++kt) {     // NOT unrolled: pbuf = q&1 is static
        #pragma unroll
        for (int q = 0; q < 4; ++q) {
            const int pbuf = q & 1;      // (kt*4+q)&1 == q&1
            if (kt < 7 || q < 3) {       // stage next phase into other buffer
                int kn = kt + (q == 3), qn = (q + 1) & 3;
                #pragma unroll
                for (int j = 0; j < 4; ++j) {
                    int idx = wid * 4 + j, pl = idx >> 4, tl = idx & 15;
                    const u16* g = (pl ? w2l : w2h) + ((size_t)(lid * 8 + kn) * 64 + qn * 16 + tl) * 512 + lane * 8;
                    glds16(g, w2b + (((pbuf ^ 1) * 2 + pl) * 16 + tl) * 512);
                }
            }
            if (q == 0) {                // h A-frags, reused across 4 quarters
                #pragma unroll
                for (int mf = 0; mf < 2; ++mf) {
                    int row = wm * 32 + mf * 16 + lr;
                    int sw  = (row & 7) << 3;
                    a2h[mf] = *(const bfv8*)(hh + row * 256 + ((kt * 32 + lg * 8) ^ sw));
                    a2l[mf] = *(const bfv8*)(hl + row * 256 + ((kt * 32 + lg * 8) ^ sw));
                }
            }
            const u16* wb2 = w2b + pbuf * 16384;
            #pragma unroll
            for (int nf = 0; nf < 4; ++nf) {
                int tl = wn * 4 + nf;
                bfv8 bh = *(const bfv8*)(wb2 + tl * 512 + lane * 8);
                bfv8 bl = *(const bfv8*)(wb2 + 8192 + tl * 512 + lane * 8);
                #pragma unroll
                for (int mf = 0; mf < 2; ++mf) {
                    acc2[mf][q][nf] = __builtin_amdgcn_mfma_f32_16x16x32_bf16(a2h[mf], bh, acc2[mf][q][nf], 0, 0, 0);
                    acc2[mf][q][nf] = __builtin_amdgcn_mfma_f32_16x16x32_bf16(a2h[mf], bl, acc2[mf][q][nf], 0, 0, 0);
                    acc2[mf][q][nf] = __builtin_amdgcn_mfma_f32_16x16x32_bf16(a2l[mf], bh, acc2[mf][q][nf], 0, 0, 0);
                }
            }
            __syncthreads();
        }
    }

    // bias + residual + LN statistics
    float s1v[2][4], s2v[2][4];
    #pragma unroll
    for (int mf = 0; mf < 2; ++mf)
        #pragma unroll
        for (int r = 0; r < 4; ++r) { s1v[mf][r] = 0.f; s2v[mf][r] = 0.f; }

    #pragma unroll
    for (int mf = 0; mf < 2; ++mf)
        #pragma unroll
        for (int q = 0; q < 4; ++q)
            #pragma unroll
            for (int nf = 0; nf < 4; ++nf) {
                int col = (q * 16 + wn * 4 + nf) * 16 + lr;
                float bb = b2[lid * H_ + col];
                #pragma unroll
                for (int r = 0; r < 4; ++r) {
                    int row = wm * 32 + mf * 16 + lg * 4 + r;
                    float x = acc2[mf][q][nf][r] + bb + Xb[(size_t)row * H_ + col];
                    acc2[mf][q][nf][r] = x;
                    s1v[mf][r] += x; s2v[mf][r] += x * x;
                }
            }

    #pragma unroll
    for (int mf = 0; mf < 2; ++mf)
        #pragma unroll
        for (int r = 0; r < 4; ++r) {
            float a = s1v[mf][r], c = s2v[mf][r];
            #pragma unroll
            for (int m = 1; m < 16; m <<= 1) { a += __shfl_xor(a, m); c += __shfl_xor(c, m); }
            if (lr == 0) {
                int row = wm * 32 + mf * 16 + lg * 4 + r;
                part[(row * 4 + wn) * 2 + 0] = a;
                part[(row * 4 + wn) * 2 + 1] = c;
            }
        }
    __syncthreads();
    if (t < 64) {
        float a = part[(t*4+0)*2] + part[(t*4+1)*2] + part[(t*4+2)*2] + part[(t*4+3)*2];
        float c = part[(t*4+0)*2+1] + part[(t*4+1)*2+1] + part[(t*4+2)*2+1] + part[(t*4+3)*2+1];
        float mean = a * (1.f / 1024.f);
        float var  = c * (1.f / 1024.f) - mean * mean;
        mrstd[t*2]   = mean;
        mrstd[t*2+1] = rsqrtf(var + 1e-5f);
    }
    __syncthreads();

    float* ob = out + ((size_t)(b * S_ + s0)) * H_;
    #pragma unroll
    for (int q = 0; q < 4; ++q)
        #pragma unroll
        for (int nf = 0; nf < 4; ++nf) {
            int col = (q * 16 + wn * 4 + nf) * 16 + lr;
            float g  = gamma[lid * H_ + col];
            float bt = beta[lid * H_ + col];
            #pragma unroll
            for (int mf = 0; mf < 2; ++mf)
                #pragma unroll
                for (int r = 0; r < 4; ++r) {
                    int row = wm * 32 + mf * 16 + lg * 4 + r;
                    float x = acc2[mf][q][nf][r];
                    ob[(size_t)row * H_ + col] = (x - mrstd[row*2]) * mrstd[row*2+1] * g + bt;
                }
        }
}

// ---------------------------------------------------------------------------
extern "C" void kernel_launch(void* const* d_in, const int* in_sizes, int n_in,
                              void* d_out, int out_size, void* d_ws, size_t ws_size,
                              hipStream_t stream)
{
    const float* X     = (const float*)d_in[0];
    const int*   langs = (const int*)  d_in[1];
    const float* W1    = (const float*)d_in[2];
    const float* b1    = (const float*)d_in[3];
    const float* W2    = (const float*)d_in[4];
    const float* b2    = (const float*)d_in[5];
    const float* gamma = (const float*)d_in[6];
    const float* beta  = (const float*)d_in[7];
    float* out = (float*)d_out;

    char* ws = (char*)d_ws;
    u16* w1h = (u16*)(ws);
    u16* w1l = (u16*)(ws + 5242880);
    u16* w2h = (u16*)(ws + 10485760);
    u16* w2l = (u16*)(ws + 15728640);   // total 20,971,520 B of d_ws

    hipFuncSetAttribute((const void*)fused_adapter,
                        hipFuncAttributeMaxDynamicSharedMemorySize, 152064);

    hipLaunchKernelGGL(pack_weights, dim3(640), dim3(256), 0, stream,
                       W1, W2, w1h, w1l, w2h, w2l);
    hipLaunchKernelGGL(fused_adapter, dim3(1024), dim3(512), 152064, stream,
                       X, langs, b1, b2, gamma, beta, w1h, w1l, w2h, w2l, out);
}

// Round 7
// 709.373 us; speedup vs baseline: 1.2486x; 1.1681x over previous
//
#include <hip/hip_runtime.h>

#define B_  32
#define S_  2048
#define H_  1024
#define A_  256
#define L_  10

typedef unsigned short u16;
typedef _Float16 f16;
typedef f16   f16v8 __attribute__((ext_vector_type(8)));
typedef float f32x4 __attribute__((ext_vector_type(4)));

typedef __attribute__((address_space(1))) const unsigned int gu32_t;
typedef __attribute__((address_space(3))) unsigned int lu32_t;
__device__ __forceinline__ void glds16(const void* g, void* l) {
    // async global->LDS, 16 B/lane; LDS dst = wave-uniform base + lane*16
    __builtin_amdgcn_global_load_lds((gu32_t*)g, (lu32_t*)l, 16, 0, 0);
}

// ---------------------------------------------------------------------------
// pack_weights (fp16, single plane): W1 [L][H][A], W2 [L][A][H] -> MFMA
// B-frag order: slot = ln*8+i <-> k = (ln>>4)*8+i, n = nt*16 + (ln&15).
// w1p: [lid][ktg 32][nt 16][512]; w2p: [lid][kt 8][nt 64][512].
// ---------------------------------------------------------------------------
__global__ __launch_bounds__(256) void pack_weights(
    const float* __restrict__ W1, const float* __restrict__ W2,
    f16* __restrict__ w1p, f16* __restrict__ w2p)
{
    const int p = blockIdx.x;
    const int t = threadIdx.x;
    const float* src; int sstride; f16* dst; size_t dbase;
    if (p < 320) {                       // W1: (lid, ktg) -> 32k x 256n patch
        int lid = p >> 5, ktg = p & 31;
        src = W1 + ((size_t)lid * H_ + ktg * 32) * A_;
        sstride = A_;
        dst = w1p; dbase = (size_t)(lid * 32 + ktg) * 8192;
    } else {                             // W2: (lid, kt, nquarter)
        int p2 = p - 320;
        int lid = p2 >> 5, kt = (p2 >> 2) & 7, nq = p2 & 3;
        src = W2 + ((size_t)lid * A_ + kt * 32) * H_ + nq * 256;
        sstride = H_;
        dst = w2p; dbase = ((size_t)(lid * 8 + kt) * 64 + nq * 16) * 512;
    }
    const int ln = t & 63;
    const int k0 = (ln >> 4) * 8;
    const int nn = ln & 15;
    #pragma unroll
    for (int r = 0; r < 4; ++r) {
        int nt = r * 4 + (t >> 6);       // tile 0..15 within the patch
        const float* s = src + (size_t)k0 * sstride + nt * 16 + nn;
        f16v8 h8;
        #pragma unroll
        for (int i = 0; i < 8; ++i) h8[i] = (f16)s[(size_t)i * sstride];
        *(f16v8*)(dst + dbase + (size_t)nt * 512 + (size_t)ln * 8) = h8;
    }
}

// ---------------------------------------------------------------------------
// Fused fp16 single-product: h = relu(X@W1+b1) in LDS;
// out = LN(X + h@W2 + b2)*gamma + beta.
// Block = 32 rows, 512 thr (8 waves, 2m x 4n). LDS 54.3 KB static, VGPR<=128
// -> 2 blocks/CU (16 waves) so barrier drains are covered by the co-block.
// Single barrier per K-step; weights double-buffered via glds16; X staged
// with distance-2 register prefetch (HBM latency covered by ~2 iterations).
// ---------------------------------------------------------------------------
__global__ __launch_bounds__(512, 4) void fused_adapter(
    const float* __restrict__ X, const int* __restrict__ langs,
    const float* __restrict__ b1, const float* __restrict__ b2,
    const float* __restrict__ gamma, const float* __restrict__ beta,
    const f16* __restrict__ w1p, const f16* __restrict__ w2p,
    float* __restrict__ out)
{
    __shared__ f16   hh[32 * 256];       // 16 KB, XOR-swizzled (k ^ ((row&7)<<3))
    __shared__ f16   xbuf[2][32][40];    // 5 KB, 80 B rows (16B-aligned, 2-way banks)
    __shared__ f16   wbuf[2][16 * 512];  // 32 KB, double-buffered weight tiles
    __shared__ float part[32][4][2];
    __shared__ float mrstd[32][2];

    // XCD-aware decode: XCD k serves batches 4k..4k+3 (weights L2-resident).
    const int fid = blockIdx.x;          // 2048 blocks
    const int uu  = fid >> 3;            // 0..255
    const int b   = (fid & 7) * 4 + (uu >> 6);
    const int s0  = (uu & 63) * 32;
    const int lid = langs[b];

    const int t = threadIdx.x, lane = t & 63, wid = t >> 6;
    const int wm = wid >> 2, wn = wid & 3;
    const int lr = lane & 15, lg = lane >> 4;

    const float* Xb = X + ((size_t)(b * S_ + s0)) * H_;
    const f16* w1base = w1p + (size_t)lid * 32 * 8192;
    const f16* w2base = w2p + (size_t)lid * 8 * 64 * 512;

    // ======================= phase 1: h = relu(X@W1+b1) =======================
    f32x4 acc1[4];
    #pragma unroll
    for (int nf = 0; nf < 4; ++nf) acc1[nf] = f32x4{0.f, 0.f, 0.f, 0.f};

    const int srow = t >> 4, skk = (t & 15) * 2;   // X staging: 32 rows x 32 k

    float2 xheld;
    { // prologue: stage kt=0 (weights + x), preload x for kt=1
        #pragma unroll
        for (int j = 0; j < 2; ++j)
            glds16(w1base + (size_t)(0 * 16 + wid * 2 + j) * 512 + lane * 8,
                   &wbuf[0][(wid * 2 + j) * 512]);
        float2 x0 = *(const float2*)(Xb + (size_t)srow * H_ + skk);
        xbuf[0][srow][skk]     = (f16)x0.x;
        xbuf[0][srow][skk + 1] = (f16)x0.y;
        xheld = *(const float2*)(Xb + (size_t)srow * H_ + 32 + skk);
    }
    __syncthreads();

    #pragma unroll 1
    for (int kt = 0; kt < 32; ++kt) {
        const int cur = kt & 1, nxt = cur ^ 1;
        if (kt < 31) {                   // weights for kt+1 -> other buffer
            #pragma unroll
            for (int j = 0; j < 2; ++j)
                glds16(w1base + ((size_t)(kt + 1) * 16 + wid * 2 + j) * 512 + lane * 8,
                       &wbuf[nxt][(wid * 2 + j) * 512]);
        }
        float2 xnew;
        if (kt < 30)                     // x for kt+2 (distance-2 prefetch)
            xnew = *(const float2*)(Xb + (size_t)srow * H_ + (kt + 2) * 32 + skk);

        const int arow = wm * 16 + lr;
        f16v8 a = *(const f16v8*)&xbuf[cur][arow][lg * 8];
        #pragma unroll
        for (int nf = 0; nf < 4; ++nf) {
            f16v8 bb = *(const f16v8*)&wbuf[cur][(wn * 4 + nf) * 512 + lane * 8];
            acc1[nf] = __builtin_amdgcn_mfma_f32_16x16x32_f16(a, bb, acc1[nf], 0, 0, 0);
        }
        if (kt < 31) {                   // write x(kt+1) to the other buffer
            xbuf[nxt][srow][skk]     = (f16)xheld.x;
            xbuf[nxt][srow][skk + 1] = (f16)xheld.y;
        }
        xheld = xnew;
        __syncthreads();                 // drains glds16(kt+1) + x writes
    }

    // epilogue-1: bias + relu -> swizzled h in LDS
    #pragma unroll
    for (int nf = 0; nf < 4; ++nf) {
        int k = wn * 64 + nf * 16 + lr;
        float bias = b1[lid * A_ + k];
        #pragma unroll
        for (int r = 0; r < 4; ++r) {
            int row = wm * 16 + lg * 4 + r;
            float v = acc1[nf][r] + bias;
            v = v > 0.f ? v : 0.f;
            hh[row * 256 + (k ^ ((row & 7) << 3))] = (f16)v;
        }
    }
    __syncthreads();                     // h visible; wbuf readers done
    // prologue-2: stage (kt=0, q=0)
    #pragma unroll
    for (int j = 0; j < 2; ++j)
        glds16(w2base + (size_t)(0 * 64 + 0 * 16 + wid * 2 + j) * 512 + lane * 8,
               &wbuf[0][(wid * 2 + j) * 512]);
    __syncthreads();                     // wbuf[0] drained

    // ======================= phase 2: x + h@W2 + b2, LN =======================
    f32x4 acc2[16];
    #pragma unroll
    for (int i = 0; i < 16; ++i) acc2[i] = f32x4{0.f, 0.f, 0.f, 0.f};

    #pragma unroll 1
    for (int kt = 0; kt < 8; ++kt) {
        const int arow = wm * 16 + lr;
        f16v8 a2 = *(const f16v8*)&hh[arow * 256 + ((kt * 32 + lg * 8) ^ ((arow & 7) << 3))];
        #pragma unroll
        for (int q = 0; q < 4; ++q) {
            const int ph = kt * 4 + q, cur = q & 1, nxt = cur ^ 1;
            if (ph < 31) {               // stage next phase
                int pn = ph + 1, kn = pn >> 2, qn = pn & 3;
                #pragma unroll
                for (int j = 0; j < 2; ++j)
                    glds16(w2base + ((size_t)kn * 64 + qn * 16 + wid * 2 + j) * 512 + lane * 8,
                           &wbuf[nxt][(wid * 2 + j) * 512]);
            }
            #pragma unroll
            for (int nf = 0; nf < 4; ++nf) {
                f16v8 bb = *(const f16v8*)&wbuf[cur][(wn * 4 + nf) * 512 + lane * 8];
                acc2[q * 4 + nf] = __builtin_amdgcn_mfma_f32_16x16x32_f16(a2, bb, acc2[q * 4 + nf], 0, 0, 0);
            }
            __syncthreads();
        }
    }

    // bias + residual + LN statistics
    float s1[4], s2[4];
    #pragma unroll
    for (int r = 0; r < 4; ++r) { s1[r] = 0.f; s2[r] = 0.f; }

    #pragma unroll
    for (int q = 0; q < 4; ++q)
        #pragma unroll
        for (int nf = 0; nf < 4; ++nf) {
            int col = (q * 16 + wn * 4 + nf) * 16 + lr;
            float bb = b2[lid * H_ + col];
            #pragma unroll
            for (int r = 0; r < 4; ++r) {
                int row = wm * 16 + lg * 4 + r;
                float x = acc2[q * 4 + nf][r] + bb + Xb[(size_t)row * H_ + col];
                acc2[q * 4 + nf][r] = x;
                s1[r] += x; s2[r] += x * x;
            }
        }

    #pragma unroll
    for (int r = 0; r < 4; ++r) {
        float a = s1[r], c = s2[r];
        #pragma unroll
        for (int m = 1; m < 16; m <<= 1) { a += __shfl_xor(a, m); c += __shfl_xor(c, m); }
        if (lr == 0) {
            int row = wm * 16 + lg * 4 + r;
            part[row][wn][0] = a; part[row][wn][1] = c;
        }
    }
    __syncthreads();
    if (t < 32) {
        float a = part[t][0][0] + part[t][1][0] + part[t][2][0] + part[t][3][0];
        float c = part[t][0][1] + part[t][1][1] + part[t][2][1] + part[t][3][1];
        float mean = a * (1.f / 1024.f);
        float var  = c * (1.f / 1024.f) - mean * mean;
        mrstd[t][0] = mean;
        mrstd[t][1] = rsqrtf(var + 1e-5f);
    }
    __syncthreads();

    float* ob = out + ((size_t)(b * S_ + s0)) * H_;
    #pragma unroll
    for (int q = 0; q < 4; ++q)
        #pragma unroll
        for (int nf = 0; nf < 4; ++nf) {
            int col = (q * 16 + wn * 4 + nf) * 16 + lr;
            float g  = gamma[lid * H_ + col];
            float bt = beta[lid * H_ + col];
            #pragma unroll
            for (int r = 0; r < 4; ++r) {
                int row = wm * 16 + lg * 4 + r;
                float x = acc2[q * 4 + nf][r];
                ob[(size_t)row * H_ + col] = (x - mrstd[row][0]) * mrstd[row][1] * g + bt;
            }
        }
}

// ---------------------------------------------------------------------------
extern "C" void kernel_launch(void* const* d_in, const int* in_sizes, int n_in,
                              void* d_out, int out_size, void* d_ws, size_t ws_size,
                              hipStream_t stream)
{
    const float* X     = (const float*)d_in[0];
    const int*   langs = (const int*)  d_in[1];
    const float* W1    = (const float*)d_in[2];
    const float* b1    = (const float*)d_in[3];
    const float* W2    = (const float*)d_in[4];
    const float* b2    = (const float*)d_in[5];
    const float* gamma = (const float*)d_in[6];
    const float* beta  = (const float*)d_in[7];
    float* out = (float*)d_out;

    char* ws = (char*)d_ws;
    f16* w1p = (f16*)(ws);               // 5,242,880 B
    f16* w2p = (f16*)(ws + 5242880);     // 5,242,880 B  (total 10.5 MB of d_ws)

    hipLaunchKernelGGL(pack_weights, dim3(640), dim3(256), 0, stream,
                       W1, W2, w1p, w2p);
    hipLaunchKernelGGL(fused_adapter, dim3(2048), dim3(512), 0, stream,
                       X, langs, b1, b2, gamma, beta, w1p, w2p, out);
}